// Round 2
// baseline (173.066 us; speedup 1.0000x reference)
//
#include <hip/hip_runtime.h>

#define KN 1000000
#define NCOLS 70400
#define SENTINEL -9999999.0f

// Order-preserving float<->uint encoding for atomicMax on floats.
__device__ __forceinline__ unsigned encodeF(float f) {
    unsigned b = __float_as_uint(f);
    return (b & 0x80000000u) ? ~b : (b | 0x80000000u);
}
__device__ __forceinline__ float decodeF(unsigned e) {
    unsigned b = (e & 0x80000000u) ? (e & 0x7fffffffu) : ~e;
    return __uint_as_float(b);
}

__global__ __launch_bounds__(256) void init_kernel(unsigned* __restrict__ outU) {
    int gid = blockIdx.x * blockDim.x + threadIdx.x;
    if (gid < NCOLS) outU[gid] = encodeF(SENTINEL);
}

// Weights are read with wave-uniform addresses (loop indices are compile-time
// constants after full unroll) -> compiler emits s_load_* into SGPRs via the
// scalar/constant cache. v_fma_f32 takes one SGPR operand directly, so the
// VALU stream is ~pure FMA and the LDS pipe is not used at all.
__global__ __launch_bounds__(256) void mlp_scatter_kernel(
    const float* __restrict__ x,      // (4, K) : input_1[0,:,0,:]
    const int*   __restrict__ tidx,   // (K, 2) int32 pairs (row, col)
    const float* __restrict__ W1, const float* __restrict__ b1,   // (18,4)
    const float* __restrict__ W2, const float* __restrict__ b2,   // (36,18)
    const float* __restrict__ W3, const float* __restrict__ b3,   // (36,36)
    const float* __restrict__ W4, const float* __restrict__ b4,   // (1,36)
    unsigned* __restrict__ outU)
{
    const int gid = blockIdx.x * blockDim.x + threadIdx.x;
    const int k0 = gid * 2;              // each thread handles elements k0, k0+1
    if (k0 >= KN) return;

    // Load the 4 input channels for both elements (coalesced float2).
    float2 xv[4];
#pragma unroll
    for (int c = 0; c < 4; ++c) xv[c] = *(const float2*)(x + c * KN + k0);

    // ---- layer 1: (18,4) ----
    float h1a[18], h1b[18];
#pragma unroll
    for (int j = 0; j < 18; ++j) {
        float w0 = W1[4 * j + 0], w1 = W1[4 * j + 1];
        float w2 = W1[4 * j + 2], w3 = W1[4 * j + 3];
        float bj = b1[j];
        float a0 = fmaf(w0, xv[0].x, fmaf(w1, xv[1].x, fmaf(w2, xv[2].x, fmaf(w3, xv[3].x, bj))));
        float a1 = fmaf(w0, xv[0].y, fmaf(w1, xv[1].y, fmaf(w2, xv[2].y, fmaf(w3, xv[3].y, bj))));
        h1a[j] = fmaxf(a0, 0.0f);
        h1b[j] = fmaxf(a1, 0.0f);
    }

    // ---- layer 2: (36,18) ----
    float h2a[36], h2b[36];
#pragma unroll
    for (int j = 0; j < 36; ++j) { float bj = b2[j]; h2a[j] = bj; h2b[j] = bj; }
#pragma unroll
    for (int i = 0; i < 18; ++i) {
        float a0 = h1a[i], a1 = h1b[i];
#pragma unroll
        for (int j = 0; j < 36; ++j) {
            float w = W2[j * 18 + i];           // uniform -> SGPR
            h2a[j] = fmaf(w, a0, h2a[j]);
            h2b[j] = fmaf(w, a1, h2b[j]);
        }
    }
#pragma unroll
    for (int j = 0; j < 36; ++j) { h2a[j] = fmaxf(h2a[j], 0.0f); h2b[j] = fmaxf(h2b[j], 0.0f); }

    // ---- layer 3: (36,36) ----
    float h3a[36], h3b[36];
#pragma unroll
    for (int j = 0; j < 36; ++j) { float bj = b3[j]; h3a[j] = bj; h3b[j] = bj; }
#pragma unroll
    for (int i = 0; i < 36; ++i) {
        float a0 = h2a[i], a1 = h2b[i];
#pragma unroll
        for (int j = 0; j < 36; ++j) {
            float w = W3[j * 36 + i];           // uniform -> SGPR
            h3a[j] = fmaf(w, a0, h3a[j]);
            h3b[j] = fmaf(w, a1, h3b[j]);
        }
    }

    // ---- layer 4: (1,36) on relu(h3) ----
    float v0 = b4[0], v1 = b4[0];
#pragma unroll
    for (int j = 0; j < 36; ++j) {
        float w = W4[j];                        // uniform -> SGPR
        v0 = fmaf(w, fmaxf(h3a[j], 0.0f), v0);
        v1 = fmaf(w, fmaxf(h3b[j], 0.0f), v1);
    }

    // ---- scatter-max on columns (row index irrelevant after row-max) ----
    int2 p0 = ((const int2*)tidx)[k0];
    int2 p1 = ((const int2*)tidx)[k0 + 1];
    atomicMax(&outU[p0.y], encodeF(v0));
    atomicMax(&outU[p1.y], encodeF(v1));
}

__global__ __launch_bounds__(256) void decode_kernel(unsigned* __restrict__ outU,
                                                     float* __restrict__ outF,
                                                     int out_size) {
    int gid = blockIdx.x * blockDim.x + threadIdx.x;
    if (gid < NCOLS) {
        outF[gid] = decodeF(outU[gid]);
    } else if (gid == NCOLS && out_size > NCOLS) {
        outF[gid] = 1.0f;  // flag
    }
}

extern "C" void kernel_launch(void* const* d_in, const int* in_sizes, int n_in,
                              void* d_out, int out_size, void* d_ws, size_t ws_size,
                              hipStream_t stream) {
    const float* input_1 = (const float*)d_in[0];   // (1,4,1,K)
    const int*   tidx    = (const int*)d_in[1];     // (K,2)
    const float* W1 = (const float*)d_in[2];
    const float* b1 = (const float*)d_in[3];
    const float* W2 = (const float*)d_in[4];
    const float* b2 = (const float*)d_in[5];
    const float* W3 = (const float*)d_in[6];
    const float* b3 = (const float*)d_in[7];
    const float* W4 = (const float*)d_in[8];
    const float* b4 = (const float*)d_in[9];

    unsigned* outU = (unsigned*)d_out;
    float*    outF = (float*)d_out;

    init_kernel<<<(NCOLS + 255) / 256, 256, 0, stream>>>(outU);

    const int nthreads = KN / 2;  // 2 elements per thread
    mlp_scatter_kernel<<<(nthreads + 255) / 256, 256, 0, stream>>>(
        input_1, tidx, W1, b1, W2, b2, W3, b3, W4, b4, outU);

    decode_kernel<<<(out_size + 255) / 256, 256, 0, stream>>>(outU, outF, out_size);
}

// Round 3
// 165.634 us; speedup vs baseline: 1.0449x; 1.0449x over previous
//
#include <hip/hip_runtime.h>

#define KN 1000000
#define NCOLS 70400
#define SENTINEL -9999999.0f

// Order-preserving float<->uint encoding for atomicMax on floats, biased so
// that enc2(SENTINEL) == 0. Then a zero-memset buffer decodes to SENTINEL.
// Monotone for all f >= SENTINEL (MLP outputs are O(1), so always true).
__device__ __forceinline__ unsigned encodeF(float f) {
    unsigned b = __float_as_uint(f);
    return (b & 0x80000000u) ? ~b : (b | 0x80000000u);
}
__device__ __forceinline__ float decodeF(unsigned e) {
    unsigned b = (e & 0x80000000u) ? (e & 0x7fffffffu) : ~e;
    return __uint_as_float(b);
}
// encodeF(-9999999.0f): bits(-9999999.0f)=0xCB18967F -> ~ = 0x34E76980
#define ENC_SENT 0x34E76980u

__global__ __launch_bounds__(256, 4) void mlp_scatter_kernel(
    const float* __restrict__ x,      // (4, K) : input_1[0,:,0,:]
    const int*   __restrict__ tidx,   // (K, 2) int32 pairs (row, col)
    const float* __restrict__ W1, const float* __restrict__ b1,   // (18,4)
    const float* __restrict__ W2, const float* __restrict__ b2,   // (36,18)
    const float* __restrict__ W3, const float* __restrict__ b3,   // (36,36)
    const float* __restrict__ W4, const float* __restrict__ b4,   // (1,36)
    unsigned* __restrict__ outU)
{
    const int k = blockIdx.x * blockDim.x + threadIdx.x;
    if (k >= KN) return;

    // 4 input channels (coalesced, stride-K rows).
    float x0 = x[0 * KN + k];
    float x1 = x[1 * KN + k];
    float x2 = x[2 * KN + k];
    float x3 = x[3 * KN + k];

    // ---- layer 1: (18,4), row-major rows contiguous ----
    float h1[18];
#pragma unroll
    for (int j = 0; j < 18; ++j) {
        float a = fmaf(W1[4 * j + 0], x0,
                  fmaf(W1[4 * j + 1], x1,
                  fmaf(W1[4 * j + 2], x2,
                  fmaf(W1[4 * j + 3], x3, b1[j]))));
        h1[j] = fmaxf(a, 0.0f);
    }

    // ---- layer 2: (36,18), j-outer dot-product form, j-pairs for ILP ----
    float h2[36];
#pragma unroll
    for (int j = 0; j < 36; j += 2) {
        float s0 = b2[j], s1 = b2[j + 1];
#pragma unroll
        for (int i = 0; i < 18; ++i) {
            float hi = h1[i];
            s0 = fmaf(W2[(j    ) * 18 + i], hi, s0);
            s1 = fmaf(W2[(j + 1) * 18 + i], hi, s1);
        }
        h2[j]     = fmaxf(s0, 0.0f);
        h2[j + 1] = fmaxf(s1, 0.0f);
    }

    // ---- layer 3 (36,36) fused with layer 4 (1,36): h3 never materialized ----
    float v = b4[0];
#pragma unroll
    for (int j = 0; j < 36; j += 2) {
        float s0 = b3[j], s1 = b3[j + 1];
#pragma unroll
        for (int i = 0; i < 36; ++i) {
            float hi = h2[i];
            s0 = fmaf(W3[(j    ) * 36 + i], hi, s0);
            s1 = fmaf(W3[(j + 1) * 36 + i], hi, s1);
        }
        v = fmaf(W4[j],     fmaxf(s0, 0.0f), v);
        v = fmaf(W4[j + 1], fmaxf(s1, 0.0f), v);
    }

    // ---- scatter-max on columns (row index irrelevant after row-max) ----
    int col = tidx[2 * k + 1];
    atomicMax(&outU[col], encodeF(v) - ENC_SENT);
}

__global__ __launch_bounds__(256) void decode_kernel(unsigned* __restrict__ outU,
                                                     float* __restrict__ outF,
                                                     int out_size) {
    int gid = blockIdx.x * blockDim.x + threadIdx.x;
    if (gid < NCOLS) {
        outF[gid] = decodeF(outU[gid] + ENC_SENT);
    } else if (gid == NCOLS && out_size > NCOLS) {
        outF[gid] = 1.0f;  // flag
    }
}

extern "C" void kernel_launch(void* const* d_in, const int* in_sizes, int n_in,
                              void* d_out, int out_size, void* d_ws, size_t ws_size,
                              hipStream_t stream) {
    const float* input_1 = (const float*)d_in[0];   // (1,4,1,K)
    const int*   tidx    = (const int*)d_in[1];     // (K,2)
    const float* W1 = (const float*)d_in[2];
    const float* b1 = (const float*)d_in[3];
    const float* W2 = (const float*)d_in[4];
    const float* b2 = (const float*)d_in[5];
    const float* W3 = (const float*)d_in[6];
    const float* b3 = (const float*)d_in[7];
    const float* W4 = (const float*)d_in[8];
    const float* b4 = (const float*)d_in[9];

    unsigned* outU = (unsigned*)d_out;
    float*    outF = (float*)d_out;

    // Zero-init: biased encoding makes 0 decode to SENTINEL.
    hipMemsetAsync(outU, 0, (size_t)NCOLS * sizeof(unsigned), stream);

    mlp_scatter_kernel<<<(KN + 255) / 256, 256, 0, stream>>>(
        input_1, tidx, W1, b1, W2, b2, W3, b3, W4, b4, outU);

    decode_kernel<<<(out_size + 255) / 256, 256, 0, stream>>>(outU, outF, out_size);
}

// Round 4
// 165.053 us; speedup vs baseline: 1.0486x; 1.0035x over previous
//
#include <hip/hip_runtime.h>

#define KN 1000000
#define NCOLS 70400
#define SENTINEL -9999999.0f

// Order-preserving float<->uint encoding for atomicMax on floats, biased so
// that encode(SENTINEL) == 0 -> a zero-memset buffer decodes to SENTINEL.
__device__ __forceinline__ unsigned encodeF(float f) {
    unsigned b = __float_as_uint(f);
    return (b & 0x80000000u) ? ~b : (b | 0x80000000u);
}
__device__ __forceinline__ float decodeF(unsigned e) {
    unsigned b = (e & 0x80000000u) ? (e & 0x7fffffffu) : ~e;
    return __uint_as_float(b);
}
// encodeF(-9999999.0f): bits = 0xCB18967F -> ~ = 0x34E76980
#define ENC_SENT 0x34E76980u

// ---- compile-time-unrolled helpers: every h[] index is a constexpr, so
// ---- SROA keeps all hidden state in VGPRs (R3's rolled loops sent h[] to
// ---- scratch: VGPR_Count=28, ~1000 scratch VMEM ops/element = the 89us).

// dual dot-product: s0 += w0.h, s1 += w1.h  (two independent FMA chains)
template<int I, int LEN, int NH>
__device__ __forceinline__ void dot2(const float* __restrict__ w0,
                                     const float* __restrict__ w1,
                                     const float (&h)[NH], float& s0, float& s1) {
    s0 = fmaf(w0[I], h[I], s0);
    s1 = fmaf(w1[I], h[I], s1);
    if constexpr (I + 1 < LEN) dot2<I + 1, LEN, NH>(w0, w1, h, s0, s1);
}

template<int J>
__device__ __forceinline__ void layer1(float (&h1)[18],
                                       const float* __restrict__ W1,
                                       const float* __restrict__ b1,
                                       float x0, float x1, float x2, float x3) {
    float a = fmaf(W1[4 * J + 0], x0,
              fmaf(W1[4 * J + 1], x1,
              fmaf(W1[4 * J + 2], x2,
              fmaf(W1[4 * J + 3], x3, b1[J]))));
    h1[J] = fmaxf(a, 0.0f);
    if constexpr (J + 1 < 18) layer1<J + 1>(h1, W1, b1, x0, x1, x2, x3);
}

template<int J>
__device__ __forceinline__ void layer2(const float (&h1)[18], float (&h2)[36],
                                       const float* __restrict__ W2,
                                       const float* __restrict__ b2) {
    float s0 = b2[J], s1 = b2[J + 1];
    dot2<0, 18, 18>(W2 + J * 18, W2 + (J + 1) * 18, h1, s0, s1);
    h2[J]     = fmaxf(s0, 0.0f);
    h2[J + 1] = fmaxf(s1, 0.0f);
    if constexpr (J + 2 < 36) layer2<J + 2>(h1, h2, W2, b2);
}

// layer 3 (36x36) fused with layer 4 (1x36): h3 never materialized
template<int J>
__device__ __forceinline__ void layer34(const float (&h2)[36], float& v,
                                        const float* __restrict__ W3,
                                        const float* __restrict__ b3,
                                        const float* __restrict__ W4) {
    float s0 = b3[J], s1 = b3[J + 1];
    dot2<0, 36, 36>(W3 + J * 36, W3 + (J + 1) * 36, h2, s0, s1);
    v = fmaf(W4[J],     fmaxf(s0, 0.0f), v);
    v = fmaf(W4[J + 1], fmaxf(s1, 0.0f), v);
    if constexpr (J + 2 < 36) layer34<J + 2>(h2, v, W3, b3, W4);
}

__global__ __launch_bounds__(256, 4) void mlp_scatter_kernel(
    const float* __restrict__ x,      // (4, K) : input_1[0,:,0,:]
    const int*   __restrict__ tidx,   // (K, 2) int32 pairs (row, col)
    const float* __restrict__ W1, const float* __restrict__ b1,   // (18,4)
    const float* __restrict__ W2, const float* __restrict__ b2,   // (36,18)
    const float* __restrict__ W3, const float* __restrict__ b3,   // (36,36)
    const float* __restrict__ W4, const float* __restrict__ b4,   // (1,36)
    unsigned* __restrict__ outU)
{
    const int k = blockIdx.x * blockDim.x + threadIdx.x;
    if (k >= KN) return;

    float x0 = x[0 * KN + k];
    float x1 = x[1 * KN + k];
    float x2 = x[2 * KN + k];
    float x3 = x[3 * KN + k];

    float h1[18];
    layer1<0>(h1, W1, b1, x0, x1, x2, x3);

    float h2[36];
    layer2<0>(h1, h2, W2, b2);

    float v = b4[0];
    layer34<0>(h2, v, W3, b3, W4);

    // scatter-max on columns (row index irrelevant after the final row-max)
    int col = tidx[2 * k + 1];
    atomicMax(&outU[col], encodeF(v) - ENC_SENT);
}

__global__ __launch_bounds__(256) void decode_kernel(unsigned* __restrict__ outU,
                                                     float* __restrict__ outF,
                                                     int out_size) {
    int gid = blockIdx.x * blockDim.x + threadIdx.x;
    if (gid < NCOLS) {
        outF[gid] = decodeF(outU[gid] + ENC_SENT);
    } else if (gid == NCOLS && out_size > NCOLS) {
        outF[gid] = 1.0f;  // flag
    }
}

extern "C" void kernel_launch(void* const* d_in, const int* in_sizes, int n_in,
                              void* d_out, int out_size, void* d_ws, size_t ws_size,
                              hipStream_t stream) {
    const float* input_1 = (const float*)d_in[0];   // (1,4,1,K)
    const int*   tidx    = (const int*)d_in[1];     // (K,2)
    const float* W1 = (const float*)d_in[2];
    const float* b1 = (const float*)d_in[3];
    const float* W2 = (const float*)d_in[4];
    const float* b2 = (const float*)d_in[5];
    const float* W3 = (const float*)d_in[6];
    const float* b3 = (const float*)d_in[7];
    const float* W4 = (const float*)d_in[8];
    const float* b4 = (const float*)d_in[9];

    unsigned* outU = (unsigned*)d_out;
    float*    outF = (float*)d_out;

    // Zero-init: biased encoding makes 0 decode to SENTINEL.
    hipMemsetAsync(outU, 0, (size_t)NCOLS * sizeof(unsigned), stream);

    mlp_scatter_kernel<<<(KN + 255) / 256, 256, 0, stream>>>(
        input_1, tidx, W1, b1, W2, b2, W3, b3, W4, b4, outU);

    decode_kernel<<<(out_size + 255) / 256, 256, 0, stream>>>(outU, outF, out_size);
}